// Round 1
// baseline (1725.166 us; speedup 1.0000x reference)
//
#include <hip/hip_runtime.h>
#include <hip/hip_bf16.h>

#define TEMP_ 0.2f

static constexpr int RPC = 32;  // rows per chunk in colsum partials

// ---- bf16 helpers (manual, branch-free RNE; inputs are never NaN) ----
__device__ __forceinline__ float blo(unsigned int u){ return __uint_as_float(u << 16); }
__device__ __forceinline__ float bhi(unsigned int u){ return __uint_as_float(u & 0xFFFF0000u); }
__device__ __forceinline__ unsigned int pack2(float a, float b){
    unsigned int ua = __float_as_uint(a), ub = __float_as_uint(b);
    ua += 0x7FFFu + ((ua >> 16) & 1u);
    ub += 0x7FFFu + ((ub >> 16) & 1u);
    return (ua >> 16) | (ub & 0xFFFF0000u);
}

// r = 1 initial scaling; stats scalars init (ws is poisoned 0xAA every call)
__global__ void init_kernel(float* r, int N, double* s, double* s2, int* mb){
    int i = blockIdx.x * blockDim.x + threadIdx.x;
    if (i < N) r[i] = 1.0f;
    if (i == 0){ *s = 0.0; *s2 = 0.0; *mb = 0x7F800000; }
}

// sum, sumsq (fp64), min over all elements
__global__ void stats_kernel(const float* __restrict__ x, long long n4,
                             double* s, double* s2, int* mb){
    long long i = blockIdx.x * (long long)blockDim.x + threadIdx.x;
    long long stride = (long long)gridDim.x * blockDim.x;
    const float4* x4 = (const float4*)x;
    double a = 0.0, b = 0.0;
    float mn = __int_as_float(0x7F800000);
    for (; i < n4; i += stride){
        float4 v = x4[i];
        a += (double)v.x + (double)v.y + (double)v.z + (double)v.w;
        b += (double)v.x * v.x + (double)v.y * v.y + (double)v.z * v.z + (double)v.w * v.w;
        mn = fminf(mn, fminf(fminf(v.x, v.y), fminf(v.z, v.w)));
    }
    #pragma unroll
    for (int off = 32; off; off >>= 1){
        a  += __shfl_down(a, off);
        b  += __shfl_down(b, off);
        mn  = fminf(mn, __shfl_down(mn, off));
    }
    __shared__ double sa[4], sb[4]; __shared__ float sm[4];
    int w = threadIdx.x >> 6, l = threadIdx.x & 63;
    if (l == 0){ sa[w] = a; sb[w] = b; sm[w] = mn; }
    __syncthreads();
    if (threadIdx.x == 0){
        int nw = blockDim.x >> 6;
        for (int k = 1; k < nw; ++k){ a += sa[k]; b += sb[k]; mn = fminf(mn, sm[k]); }
        atomicAdd(s, a);
        atomicAdd(s2, b);
        atomicMin(mb, __float_as_int(mn));  // valid: all inputs >= 0
    }
}

// coefs[0] = 1/(std*TEMP), coefs[1] = min  =>  q = exp((min - x) * a)
__global__ void finalize_kernel(const double* s, const double* s2, const int* mb,
                                double n, float* coefs){
    double mean = *s / n;
    double var  = *s2 / n - mean * mean;
    double stdv = sqrt(var * (n / (n - 1.0)));   // unbiased (ddof=1)
    coefs[0] = (float)(1.0 / (stdv * (double)TEMP_));
    coefs[1] = __int_as_float(*mb);
}

// q~ = bf16(exp((min - x) * a)), 8 elements / thread
__global__ void build_q_kernel(const float* __restrict__ x, unsigned int* __restrict__ q,
                               const float* __restrict__ coefs, long long n){
    float a = coefs[0], mv = coefs[1];
    long long i = (blockIdx.x * (long long)blockDim.x + threadIdx.x) * 8;
    if (i >= n) return;
    float4 v0 = *(const float4*)(x + i);
    float4 v1 = *(const float4*)(x + i + 4);
    float q0 = __expf((mv - v0.x) * a), q1 = __expf((mv - v0.y) * a);
    float q2 = __expf((mv - v0.z) * a), q3 = __expf((mv - v0.w) * a);
    float q4 = __expf((mv - v1.x) * a), q5 = __expf((mv - v1.y) * a);
    float q6 = __expf((mv - v1.z) * a), q7 = __expf((mv - v1.w) * a);
    uint4 o;
    o.x = pack2(q0, q1); o.y = pack2(q2, q3); o.z = pack2(q4, q5); o.w = pack2(q6, q7);
    *(uint4*)(q + (i >> 1)) = o;
}

// partial column sums of r_i * q_ij; block = (col group of 2048, row chunk of RPC)
// deterministic: writes per-chunk partials to P, no atomics
template<bool USE_Q>
__global__ void colsum_kernel(const unsigned int* __restrict__ q, const float* __restrict__ x,
                              const float* __restrict__ coefs, const float* __restrict__ r,
                              float* __restrict__ P, int M){
    int j0   = blockIdx.x * 2048 + threadIdx.x * 8;
    int row0 = blockIdx.y * RPC;
    float a = 0.f, mv = 0.f;
    if (!USE_Q){ a = coefs[0]; mv = coefs[1]; }
    float acc[8] = {0,0,0,0,0,0,0,0};
    for (int it = 0; it < RPC; ++it){
        int row = row0 + it;
        float rv = r[row];
        long long base = (long long)row * M + j0;
        if (USE_Q){
            uint4 qq = *(const uint4*)(q + (base >> 1));
            acc[0] += rv * blo(qq.x); acc[1] += rv * bhi(qq.x);
            acc[2] += rv * blo(qq.y); acc[3] += rv * bhi(qq.y);
            acc[4] += rv * blo(qq.z); acc[5] += rv * bhi(qq.z);
            acc[6] += rv * blo(qq.w); acc[7] += rv * bhi(qq.w);
        } else {
            float4 v0 = *(const float4*)(x + base);
            float4 v1 = *(const float4*)(x + base + 4);
            acc[0] += rv * __expf((mv - v0.x) * a); acc[1] += rv * __expf((mv - v0.y) * a);
            acc[2] += rv * __expf((mv - v0.z) * a); acc[3] += rv * __expf((mv - v0.w) * a);
            acc[4] += rv * __expf((mv - v1.x) * a); acc[5] += rv * __expf((mv - v1.y) * a);
            acc[6] += rv * __expf((mv - v1.z) * a); acc[7] += rv * __expf((mv - v1.w) * a);
        }
    }
    float* Pr = P + (long long)blockIdx.y * M + j0;
    *(float4*)(Pr)     = make_float4(acc[0], acc[1], acc[2], acc[3]);
    *(float4*)(Pr + 4) = make_float4(acc[4], acc[5], acc[6], acc[7]);
}

// c_j = B_j / sum_rc P[rc][j]
__global__ void colfin_kernel(const float* __restrict__ Bv, const float* __restrict__ P,
                              float* __restrict__ c, int M, int RC){
    int j = blockIdx.x * blockDim.x + threadIdx.x;
    if (j >= M) return;
    float s = 0.f;
    for (int rc = 0; rc < RC; ++rc) s += P[(long long)rc * M + j];
    c[j] = Bv[j] / s;
}

// v_i = sum_j q_ij * c_j ; one wave per row, no atomics
template<bool USE_Q>
__global__ void rowsum_kernel(const unsigned int* __restrict__ q, const float* __restrict__ x,
                              const float* __restrict__ coefs, const float* __restrict__ c,
                              float* __restrict__ v, int M){
    int gid  = blockIdx.x * blockDim.x + threadIdx.x;
    int row  = gid >> 6;
    int lane = gid & 63;
    float a = 0.f, mv = 0.f;
    if (!USE_Q){ a = coefs[0]; mv = coefs[1]; }
    long long base = (long long)row * M;
    float acc = 0.f;
    for (int j = lane * 8; j < M; j += 512){
        float4 c0 = *(const float4*)(c + j);
        float4 c1 = *(const float4*)(c + j + 4);
        if (USE_Q){
            uint4 qq = *(const uint4*)(q + ((base + j) >> 1));
            acc += blo(qq.x) * c0.x + bhi(qq.x) * c0.y + blo(qq.y) * c0.z + bhi(qq.y) * c0.w
                 + blo(qq.z) * c1.x + bhi(qq.z) * c1.y + blo(qq.w) * c1.z + bhi(qq.w) * c1.w;
        } else {
            float4 v0 = *(const float4*)(x + base + j);
            float4 v1 = *(const float4*)(x + base + j + 4);
            acc += __expf((mv - v0.x) * a) * c0.x + __expf((mv - v0.y) * a) * c0.y
                 + __expf((mv - v0.z) * a) * c0.z + __expf((mv - v0.w) * a) * c0.w
                 + __expf((mv - v1.x) * a) * c1.x + __expf((mv - v1.y) * a) * c1.y
                 + __expf((mv - v1.z) * a) * c1.z + __expf((mv - v1.w) * a) * c1.w;
        }
    }
    #pragma unroll
    for (int off = 32; off; off >>= 1) acc += __shfl_down(acc, off);
    if (lane == 0) v[row] = acc;
}

// r_i = A_i / v_i
__global__ void rowfin_kernel(const float* __restrict__ Av, const float* __restrict__ vv,
                              float* __restrict__ r, int N){
    int i = blockIdx.x * blockDim.x + threadIdx.x;
    if (i < N) r[i] = Av[i] / vv[i];
}

// T_ij = r_i * exp((min - x_ij)*a) * c_j  — exact exp from fp32 cdist
__global__ void final_kernel(const float* __restrict__ x, const float* __restrict__ coefs,
                             const float* __restrict__ r, const float* __restrict__ c,
                             float* __restrict__ out, int M){
    long long i = (blockIdx.x * (long long)blockDim.x + threadIdx.x) * 4;
    int row = (int)(i / M);
    int j   = (int)(i - (long long)row * M);
    float a = coefs[0], mv = coefs[1];
    float rv = r[row];
    float4 v  = *(const float4*)(x + i);
    float4 cc = *(const float4*)(c + j);
    float4 o;
    o.x = rv * cc.x * __expf((mv - v.x) * a);
    o.y = rv * cc.y * __expf((mv - v.y) * a);
    o.z = rv * cc.z * __expf((mv - v.z) * a);
    o.w = rv * cc.w * __expf((mv - v.w) * a);
    *(float4*)(out + i) = o;
}

extern "C" void kernel_launch(void* const* d_in, const int* in_sizes, int n_in,
                              void* d_out, int out_size, void* d_ws, size_t ws_size,
                              hipStream_t stream){
    const float* x  = (const float*)d_in[0];
    const float* Av = (const float*)d_in[1];
    const float* Bv = (const float*)d_in[2];
    float* out = (float*)d_out;
    int N = in_sizes[1], M = in_sizes[2];
    long long NM = (long long)N * M;

    char* ws = (char*)d_ws;
    double* s    = (double*)(ws + 0);
    double* s2   = (double*)(ws + 8);
    int*    mb   = (int*)   (ws + 16);
    float*  coefs= (float*) (ws + 24);
    size_t off = 64;
    float* v = (float*)(ws + off); off += (size_t)N * 4;
    float* r = (float*)(ws + off); off += (size_t)N * 4;
    float* c = (float*)(ws + off); off += (size_t)M * 4;
    int RC = N / RPC;
    float* P = (float*)(ws + off); off += (size_t)RC * M * 4;
    off = (off + 255) & ~(size_t)255;
    unsigned int* q = (unsigned int*)(ws + off);
    const bool use_q = (ws_size >= off + (size_t)NM * 2);  // bf16 Q cache fits?

    init_kernel<<<(N + 255) / 256, 256, 0, stream>>>(r, N, s, s2, mb);
    stats_kernel<<<2048, 256, 0, stream>>>(x, NM >> 2, s, s2, mb);
    finalize_kernel<<<1, 1, 0, stream>>>(s, s2, mb, (double)NM, coefs);
    if (use_q)
        build_q_kernel<<<(int)(NM / 8 / 256), 256, 0, stream>>>(x, q, coefs, NM);

    dim3 cgrid(M / 2048, RC);
    int rgrid = N / 4;  // one wave per row, 4 waves/block
    for (int it = 0; it < 10; ++it){
        if (use_q) colsum_kernel<true ><<<cgrid, 256, 0, stream>>>(q, x, coefs, r, P, M);
        else       colsum_kernel<false><<<cgrid, 256, 0, stream>>>(q, x, coefs, r, P, M);
        colfin_kernel<<<(M + 255) / 256, 256, 0, stream>>>(Bv, P, c, M, RC);
        if (use_q) rowsum_kernel<true ><<<rgrid, 256, 0, stream>>>(q, x, coefs, c, v, M);
        else       rowsum_kernel<false><<<rgrid, 256, 0, stream>>>(q, x, coefs, c, v, M);
        rowfin_kernel<<<(N + 255) / 256, 256, 0, stream>>>(Av, v, r, N);
    }
    final_kernel<<<(int)(NM / 4 / 256), 256, 0, stream>>>(x, coefs, r, c, out, M);
}